// Round 16
// baseline (131.232 us; speedup 1.0000x reference)
//
#include <hip/hip_runtime.h>
#include <hip/hip_bf16.h>

static constexpr int NN  = 50000;  // nodes
static constexpr int KNB = 32;     // neighbors
static constexpr int F   = 128;    // features
static constexpr int E   = 8;      // edge features
static constexpr int TI  = 16;     // nodes per block (3125 blocks)
static constexpr int LN  = F * E;  // 1024 contraction length

typedef __attribute__((ext_vector_type(8))) short short8v;
typedef __attribute__((ext_vector_type(4))) float f32x4;

__device__ __forceinline__ unsigned short f2bf(float x) {
    unsigned u = __float_as_uint(x);
    unsigned r = (u + 0x7fff + ((u >> 16) & 1)) >> 16;   // RNE
    return (unsigned short)r;
}

// ---------- prep A: w[l,m,n] -> W2f bf16 in B-fragment order ----------
// W2f[((kb*128 + m)*4 + kq)*8 + e8] = bf16( w[l,m,n] ) where
//   k = kb*32 + kq*4 + (e8&3) + (e8>>2)*16 ,  l = k>>3, n = k&7
__global__ void prep_w_kernel(const float* __restrict__ w, unsigned short* __restrict__ w2f) {
    int o  = blockIdx.x * 256 + threadIdx.x;          // 131072 total
    int e8 = o & 7, kq = (o >> 3) & 3, m = (o >> 5) & 127, kb = o >> 12;
    int k  = kb * 32 + kq * 4 + (e8 & 3) + ((e8 >> 2) << 4);
    int l  = k >> 3, n = k & 7;
    w2f[o] = f2bf(w[(size_t)(l * F + m) * E + n]);
}

// Early-clobber ("=&v") REQUIRED (R12 crash: output aliased later addr input).
// dwordx2: 8B/lane x 64 lanes = 512B = ONE full fp32 node row per instruction.
#define ISSUE8(GS)                                                         \
    asm volatile(                                                          \
        "global_load_dwordx2 %0, %8, %16\n\t"                              \
        "global_load_dwordx2 %1, %9, %16\n\t"                              \
        "global_load_dwordx2 %2, %10, %16\n\t"                             \
        "global_load_dwordx2 %3, %11, %16\n\t"                             \
        "global_load_dwordx2 %4, %12, %16\n\t"                             \
        "global_load_dwordx2 %5, %13, %16\n\t"                             \
        "global_load_dwordx2 %6, %14, %16\n\t"                             \
        "global_load_dwordx2 %7, %15, %16"                                 \
        : "=&v"(g[(GS)+0]), "=&v"(g[(GS)+1]), "=&v"(g[(GS)+2]), "=&v"(g[(GS)+3]), \
          "=&v"(g[(GS)+4]), "=&v"(g[(GS)+5]), "=&v"(g[(GS)+6]), "=&v"(g[(GS)+7])  \
        : "v"(vo[0]), "v"(vo[1]), "v"(vo[2]), "v"(vo[3]),                  \
          "v"(vo[4]), "v"(vo[5]), "v"(vo[6]), "v"(vo[7]),                  \
          "s"(nodes)                                                       \
        : "memory")

#define MKVO(JB)                                                           \
    _Pragma("unroll")                                                      \
    for (int q = 0; q < 8; ++q) {                                          \
        unsigned idx = (unsigned)nl[(JB) + q];     /* uniform -> s_load */ \
        if (idx >= (unsigned)NN) idx = 0u;         /* scalar clamp */      \
        vo[q] = idx * 512u + lane8;                                        \
    }

#define WAIT8(NSTR, GS)                                                    \
    asm volatile("s_waitcnt vmcnt(" NSTR ")"                               \
        : "+v"(g[(GS)+0]), "+v"(g[(GS)+1]), "+v"(g[(GS)+2]), "+v"(g[(GS)+3]),  \
          "+v"(g[(GS)+4]), "+v"(g[(GS)+5]), "+v"(g[(GS)+6]), "+v"(g[(GS)+7])   \
        :: "memory")

#define CONSUME8(JB, GS)                                                   \
    _Pragma("unroll")                                                      \
    for (int q = 0; q < 8; ++q) {                                          \
        const int j = (JB) + q;                                            \
        const float v0 = g[(GS) + q].x;            /* no unpack needed */  \
        const float v1 = g[(GS) + q].y;                                    \
        const float4 e0 = *(const float4*)(ep + j * 8);   /* uniform */    \
        const float4 e1 = *(const float4*)(ep + j * 8 + 4);                \
        a0[0] = __builtin_fmaf(e0.x, v0, a0[0]); a1[0] = __builtin_fmaf(e0.x, v1, a1[0]); \
        a0[1] = __builtin_fmaf(e0.y, v0, a0[1]); a1[1] = __builtin_fmaf(e0.y, v1, a1[1]); \
        a0[2] = __builtin_fmaf(e0.z, v0, a0[2]); a1[2] = __builtin_fmaf(e0.z, v1, a1[2]); \
        a0[3] = __builtin_fmaf(e0.w, v0, a0[3]); a1[3] = __builtin_fmaf(e0.w, v1, a1[3]); \
        a0[4] = __builtin_fmaf(e1.x, v0, a0[4]); a1[4] = __builtin_fmaf(e1.x, v1, a1[4]); \
        a0[5] = __builtin_fmaf(e1.y, v0, a0[5]); a1[5] = __builtin_fmaf(e1.y, v1, a1[5]); \
        a0[6] = __builtin_fmaf(e1.z, v0, a0[6]); a1[6] = __builtin_fmaf(e1.z, v1, a1[6]); \
        a0[7] = __builtin_fmaf(e1.w, v0, a0[7]); a1[7] = __builtin_fmaf(e1.w, v1, a1[7]); \
    }

// ---------- main fused kernel ----------
// R14 structure verbatim (512 thr / 8 waves, T 32 KiB swizzled, stage-2
// unchanged); stage-1 gathers fp32 node rows directly (dwordx2, 16-deep
// forced rolling window, counted vmcnt(8) rolls). No prep_nodes kernel.
__global__ __launch_bounds__(512, 8)
void mp_main_kernel(const float* __restrict__ nodes,
                    const int*   __restrict__ nlist,
                    const float* __restrict__ edges,
                    const float* __restrict__ inv_degree,
                    const unsigned short* __restrict__ w2f,
                    float* __restrict__ out)
{
    __shared__ unsigned short tS[TI * LN];            // 32 KiB T (swizzled, R7 layout)
    const int tid    = threadIdx.x;
    const int wv     = __builtin_amdgcn_readfirstlane(tid >> 6);   // wave id 0..7
    const int lane   = tid & 63;
    const int i_base = blockIdx.x * TI;
    char* tB = (char*)tS;
    const unsigned lane8 = (unsigned)lane * 8u;

    // ---------------- stage 1: 2 rows per wave, 16-deep rolling window ----------------
    for (int it = 0; it < 2; ++it) {
        const int row = wv * 2 + it;                  // uniform 0..15
        const int i   = i_base + row;
        const int*   nl = nlist + (size_t)i * KNB;
        const float* ep = edges + (size_t)i * (KNB * E);

        float a0[E], a1[E];
        #pragma unroll
        for (int n = 0; n < E; ++n) { a0[n] = 0.f; a1[n] = 0.f; }

        float2 g[16];
        unsigned vo[8];
        MKVO(0);  ISSUE8(0);                          //  8 in flight (j 0-7)
        MKVO(8);  ISSUE8(8);                          // 16 in flight (j 8-15)
        WAIT8("8", 0);  CONSUME8(0, 0);               // j0-7 landed; 8 flying
        MKVO(16); ISSUE8(0);                          // 16 in flight (j16-23 -> g[0..7])
        WAIT8("8", 8);  CONSUME8(8, 8);               // j8-15 landed; 8 flying
        MKVO(24); ISSUE8(8);                          // 16 in flight (j24-31 -> g[8..15])
        WAIT8("8", 0);  CONSUME8(16, 0);              // j16-23 landed; 8 flying
        WAIT8("0", 8);  CONSUME8(24, 8);              // all done

        // pack 16 bf16 (ln = lane*16 + 0..15 of row), swizzled 16B-slot store (R7)
        uint4 pk0, pk1;
        asm("v_cvt_pk_bf16_f32 %0, %1, %2" : "=v"(pk0.x) : "v"(a0[0]), "v"(a0[1]));
        asm("v_cvt_pk_bf16_f32 %0, %1, %2" : "=v"(pk0.y) : "v"(a0[2]), "v"(a0[3]));
        asm("v_cvt_pk_bf16_f32 %0, %1, %2" : "=v"(pk0.z) : "v"(a0[4]), "v"(a0[5]));
        asm("v_cvt_pk_bf16_f32 %0, %1, %2" : "=v"(pk0.w) : "v"(a0[6]), "v"(a0[7]));
        asm("v_cvt_pk_bf16_f32 %0, %1, %2" : "=v"(pk1.x) : "v"(a1[0]), "v"(a1[1]));
        asm("v_cvt_pk_bf16_f32 %0, %1, %2" : "=v"(pk1.y) : "v"(a1[2]), "v"(a1[3]));
        asm("v_cvt_pk_bf16_f32 %0, %1, %2" : "=v"(pk1.z) : "v"(a1[4]), "v"(a1[5]));
        asm("v_cvt_pk_bf16_f32 %0, %1, %2" : "=v"(pk1.w) : "v"(a1[6]), "v"(a1[7]));
        const int p2 = (lane >> 2) & 1;
        const int s  = (row & 7) << 4;
        const int rb = row * (LN * 2);
        const uint4 first  = p2 ? pk1 : pk0;
        const uint4 second = p2 ? pk0 : pk1;
        *(uint4*)(tB + rb + ((lane * 32 + (p2 << 4))      ^ s)) = first;
        *(uint4*)(tB + rb + ((lane * 32 + 16 - (p2 << 4)) ^ s)) = second;
    }
    __syncthreads();

    // ---------------- stage 2: MFMA, one 16x16 m-tile per wave (R7 verbatim) ----------------
    const int colm = lane & 15;                       // i-row for A, m-col for B/C
    const int kq   = lane >> 4;
    const int mt   = wv;                              // m-tile 0..7

    f32x4 c0 = {0.f, 0.f, 0.f, 0.f};

    const int arow = colm * (LN * 2);
    const int asw  = (colm & 7) << 4;

    #pragma unroll 4
    for (int kb = 0; kb < LN / 32; ++kb) {
        union { short8v v; uint2 u[2]; } af;
        af.u[0] = *(const uint2*)(tB + arow + ((kb * 64      + kq * 8) ^ asw)); // k=kb*32+kq*4+e
        af.u[1] = *(const uint2*)(tB + arow + ((kb * 64 + 32 + kq * 8) ^ asw)); // k=kb*32+16+kq*4+e
        union { short8v v; uint4 u; } b0;
        b0.u = *(const uint4*)(w2f + ((size_t)((kb * 128 + mt * 16 + colm) * 4 + kq)) * 8);
        c0 = __builtin_amdgcn_mfma_f32_16x16x32_bf16(af.v, b0.v, c0, 0, 0, 0);
    }

    // C/D: col = lane&15, row = (lane>>4)*4 + r   [measured m89]
    #pragma unroll
    for (int r = 0; r < 4; ++r) {
        const int ii = kq * 4 + r;
        const int gi = i_base + ii;
        out[(size_t)gi * F + mt * 16 + colm] = inv_degree[gi] * c0[r];
    }
}

// ---------- fallback (round-1 kernel, pure fp32) for tiny ws ----------
__global__ __launch_bounds__(256, 2)
void mp_fused_fallback(const float* __restrict__ nodes, const int* __restrict__ nlist,
                       const float* __restrict__ edges, const float* __restrict__ inv_degree,
                       const float* __restrict__ w, float* __restrict__ out)
{
    __shared__ float tLds[TI * F * E];
    const int tid = threadIdx.x;
    const int i_base = blockIdx.x * TI;
    {
        const int l = tid & (F - 1);
        const int half = __builtin_amdgcn_readfirstlane(tid >> 7);
        for (int g = 0; g < TI / 2; ++g) {
            const int ii = g * 2 + half;
            const int i = i_base + ii;
            float acc[E];
            #pragma unroll
            for (int n = 0; n < E; ++n) acc[n] = 0.f;
            const int* nl = nlist + i * KNB;
            const float* ep = edges + (size_t)i * (KNB * E);
            #pragma unroll 4
            for (int j = 0; j < KNB; ++j) {
                unsigned idx = (unsigned)nl[j];
                if (idx >= (unsigned)NN) idx = 0u;
                const float v = nodes[idx * F + l];
                #pragma unroll
                for (int n = 0; n < E; ++n) acc[n] = __builtin_fmaf(ep[j * E + n], v, acc[n]);
            }
            float4* dst = (float4*)&tLds[ii * (F * E) + l * E];
            dst[0] = make_float4(acc[0], acc[1], acc[2], acc[3]);
            dst[1] = make_float4(acc[4], acc[5], acc[6], acc[7]);
        }
    }
    __syncthreads();
    const int m_lo = tid & 63;
    const int q = __builtin_amdgcn_readfirstlane(tid >> 6);
    float accA[TI], accB[TI];
    #pragma unroll
    for (int ii = 0; ii < TI; ++ii) { accA[ii] = 0.f; accB[ii] = 0.f; }
    for (int lq = 0; lq < F / 4; ++lq) {
        const int l = q * (F / 4) + lq;
        const float4* wp0 = (const float4*)&w[(size_t)l * (F * E) + (size_t)m_lo * E];
        const float4* wp1 = (const float4*)&w[(size_t)l * (F * E) + (size_t)(m_lo + 64) * E];
        const float4 w0a = wp0[0], w0b = wp0[1];
        const float4 w1a = wp1[0], w1b = wp1[1];
        #pragma unroll
        for (int ii = 0; ii < TI; ++ii) {
            const float4* tp = (const float4*)&tLds[ii * (F * E) + l * E];
            const float4 ta = tp[0], tb = tp[1];
            float sA = accA[ii], sB = accB[ii];
            sA = __builtin_fmaf(ta.x, w0a.x, sA); sA = __builtin_fmaf(ta.y, w0a.y, sA);
            sA = __builtin_fmaf(ta.z, w0a.z, sA); sA = __builtin_fmaf(ta.w, w0a.w, sA);
            sA = __builtin_fmaf(tb.x, w0b.x, sA); sA = __builtin_fmaf(tb.y, w0b.y, sA);
            sA = __builtin_fmaf(tb.z, w0b.z, sA); sA = __builtin_fmaf(tb.w, w0b.w, sA);
            sB = __builtin_fmaf(ta.x, w1a.x, sB); sB = __builtin_fmaf(ta.y, w1a.y, sB);
            sB = __builtin_fmaf(ta.z, w1a.z, sB); sB = __builtin_fmaf(ta.w, w1a.w, sB);
            sB = __builtin_fmaf(tb.x, w1b.x, sB); sB = __builtin_fmaf(tb.y, w1b.y, sB);
            sB = __builtin_fmaf(tb.z, w1b.z, sB); sB = __builtin_fmaf(tb.w, w1b.w, sB);
            accA[ii] = sA; accB[ii] = sB;
        }
    }
    __syncthreads();
    float* pLds = tLds;
    #pragma unroll
    for (int ii = 0; ii < TI; ++ii) {
        pLds[q * (TI * F) + ii * F + m_lo] = accA[ii];
        pLds[q * (TI * F) + ii * F + m_lo + 64] = accB[ii];
    }
    __syncthreads();
    #pragma unroll
    for (int r = 0; r < (TI * F) / 256; ++r) {
        const int o = r * 256 + tid;
        const int ii = o >> 7;
        const int m = o & (F - 1);
        const float s = pLds[0 * (TI * F) + ii * F + m] + pLds[1 * (TI * F) + ii * F + m]
                      + pLds[2 * (TI * F) + ii * F + m] + pLds[3 * (TI * F) + ii * F + m];
        const int i = i_base + ii;
        out[(size_t)i * F + m] = inv_degree[i] * s;
    }
}

extern "C" void kernel_launch(void* const* d_in, const int* in_sizes, int n_in,
                              void* d_out, int out_size, void* d_ws, size_t ws_size,
                              hipStream_t stream) {
    const float* nodes      = (const float*)d_in[0];
    const int*   nlist      = (const int*)d_in[1];
    const float* edges      = (const float*)d_in[2];
    const float* inv_degree = (const float*)d_in[3];
    const float* w          = (const float*)d_in[4];
    float* out = (float*)d_out;
    (void)in_sizes; (void)n_in; (void)out_size;

    const size_t need_w2 = (size_t)LN * F * 2;                  // 256 KiB

    if (ws_size < need_w2) {
        mp_fused_fallback<<<dim3(NN / TI), dim3(256), 0, stream>>>(
            nodes, nlist, edges, inv_degree, w, out);
        return;
    }
    unsigned short* w2f = (unsigned short*)d_ws;

    prep_w_kernel<<<dim3((LN * F) / 256), dim3(256), 0, stream>>>(w, w2f);
    mp_main_kernel<<<dim3(NN / TI), dim3(512), 0, stream>>>(
        nodes, nlist, edges, inv_degree, w2f, out);
}

// Round 17
// 90.038 us; speedup vs baseline: 1.4575x; 1.4575x over previous
//
#include <hip/hip_runtime.h>
#include <hip/hip_bf16.h>

static constexpr int NN  = 50000;  // nodes
static constexpr int KNB = 32;     // neighbors
static constexpr int F   = 128;    // features
static constexpr int E   = 8;      // edge features
static constexpr int TI  = 16;     // nodes per block (3125 blocks)
static constexpr int LN  = F * E;  // 1024 contraction length

typedef __attribute__((ext_vector_type(8))) short short8v;
typedef __attribute__((ext_vector_type(4))) float f32x4;

__device__ __forceinline__ unsigned short f2bf(float x) {
    unsigned u = __float_as_uint(x);
    unsigned r = (u + 0x7fff + ((u >> 16) & 1)) >> 16;   // RNE
    return (unsigned short)r;
}
__device__ __forceinline__ float bf2f_lo(unsigned g) { return __uint_as_float(g << 16); }
__device__ __forceinline__ float bf2f_hi(unsigned g) { return __uint_as_float(g & 0xffff0000u); }

// ---------- merged prep: one launch does both conversions ----------
// blocks [0,512):    w[l,m,n] -> W2f bf16 in B-fragment order
//   W2f[((kb*128+m)*4+kq)*8+e8] = bf16(w[l,m,n]), k = kb*32+kq*4+(e8&3)+(e8>>2)*16
// blocks [512,3637): nodes fp32 -> bf16 packed (8 elems/thread, exact cover)
__global__ void prep_all_kernel(const float* __restrict__ w, unsigned short* __restrict__ w2f,
                                const float* __restrict__ nodes, unsigned short* __restrict__ nb) {
    const int b = blockIdx.x;
    if (b < 512) {
        int o  = b * 256 + threadIdx.x;               // 131072 total
        int e8 = o & 7, kq = (o >> 3) & 3, m = (o >> 5) & 127, kb = o >> 12;
        int k  = kb * 32 + kq * 4 + (e8 & 3) + ((e8 >> 2) << 4);
        int l  = k >> 3, n = k & 7;
        w2f[o] = f2bf(w[(size_t)(l * F + m) * E + n]);
    } else {
        int t = (b - 512) * 256 + threadIdx.x;        // 800000 threads x 8 elems = exact
        const float4* s = (const float4*)nodes + (size_t)t * 2;
        float4 a = s[0], c = s[1];
        uint4 pk;
        pk.x = (unsigned)f2bf(a.x) | ((unsigned)f2bf(a.y) << 16);
        pk.y = (unsigned)f2bf(a.z) | ((unsigned)f2bf(a.w) << 16);
        pk.z = (unsigned)f2bf(c.x) | ((unsigned)f2bf(c.y) << 16);
        pk.w = (unsigned)f2bf(c.z) | ((unsigned)f2bf(c.w) << 16);
        ((uint4*)nb)[t] = pk;
    }
}

// Early-clobber ("=&v") REQUIRED (R12 crash: output aliased later addr input).
#define ISSUE8(GS)                                                         \
    asm volatile(                                                          \
        "global_load_dword %0, %8, %16\n\t"                                \
        "global_load_dword %1, %9, %16\n\t"                                \
        "global_load_dword %2, %10, %16\n\t"                               \
        "global_load_dword %3, %11, %16\n\t"                               \
        "global_load_dword %4, %12, %16\n\t"                               \
        "global_load_dword %5, %13, %16\n\t"                               \
        "global_load_dword %6, %14, %16\n\t"                               \
        "global_load_dword %7, %15, %16"                                   \
        : "=&v"(g[(GS)+0]), "=&v"(g[(GS)+1]), "=&v"(g[(GS)+2]), "=&v"(g[(GS)+3]), \
          "=&v"(g[(GS)+4]), "=&v"(g[(GS)+5]), "=&v"(g[(GS)+6]), "=&v"(g[(GS)+7])  \
        : "v"(vo[0]), "v"(vo[1]), "v"(vo[2]), "v"(vo[3]),                  \
          "v"(vo[4]), "v"(vo[5]), "v"(vo[6]), "v"(vo[7]),                  \
          "s"(nodesBf)                                                     \
        : "memory")

#define MKVO(JB)                                                           \
    _Pragma("unroll")                                                      \
    for (int q = 0; q < 8; ++q) {                                          \
        unsigned idx = (unsigned)nl[(JB) + q];     /* uniform -> s_load */ \
        if (idx >= (unsigned)NN) idx = 0u;                                 \
        vo[q] = idx * 256u + lane4;                                        \
    }

#define WAIT8(NSTR, GS)                                                    \
    asm volatile("s_waitcnt vmcnt(" NSTR ")"                               \
        : "+v"(g[(GS)+0]), "+v"(g[(GS)+1]), "+v"(g[(GS)+2]), "+v"(g[(GS)+3]),  \
          "+v"(g[(GS)+4]), "+v"(g[(GS)+5]), "+v"(g[(GS)+6]), "+v"(g[(GS)+7])   \
        :: "memory")

#define CONSUME8(JB, GS)                                                   \
    _Pragma("unroll")                                                      \
    for (int q = 0; q < 8; ++q) {                                          \
        const int j = (JB) + q;                                            \
        const float v0 = bf2f_lo(g[(GS) + q]);                             \
        const float v1 = bf2f_hi(g[(GS) + q]);                             \
        const float4 e0 = *(const float4*)(ep + j * 8);   /* uniform */    \
        const float4 e1 = *(const float4*)(ep + j * 8 + 4);                \
        a0[0] = __builtin_fmaf(e0.x, v0, a0[0]); a1[0] = __builtin_fmaf(e0.x, v1, a1[0]); \
        a0[1] = __builtin_fmaf(e0.y, v0, a0[1]); a1[1] = __builtin_fmaf(e0.y, v1, a1[1]); \
        a0[2] = __builtin_fmaf(e0.z, v0, a0[2]); a1[2] = __builtin_fmaf(e0.z, v1, a1[2]); \
        a0[3] = __builtin_fmaf(e0.w, v0, a0[3]); a1[3] = __builtin_fmaf(e0.w, v1, a1[3]); \
        a0[4] = __builtin_fmaf(e1.x, v0, a0[4]); a1[4] = __builtin_fmaf(e1.x, v1, a1[4]); \
        a0[5] = __builtin_fmaf(e1.y, v0, a0[5]); a1[5] = __builtin_fmaf(e1.y, v1, a1[5]); \
        a0[6] = __builtin_fmaf(e1.z, v0, a0[6]); a1[6] = __builtin_fmaf(e1.z, v1, a1[6]); \
        a0[7] = __builtin_fmaf(e1.w, v0, a0[7]); a1[7] = __builtin_fmaf(e1.w, v1, a1[7]); \
    }

// ---------- main fused kernel (R14 verbatim) ----------
// 512 thr / 8 waves, T 32 KiB swizzled, 4 blocks/CU. Stage 1: per row,
// 16-deep rolling gather window (2 live bursts of 8 forced via inline asm,
// counted vmcnt(8) rolls, g-slot reuse after consumption).
__global__ __launch_bounds__(512, 8)
void mp_main_kernel(const unsigned short* __restrict__ nodesBf,
                    const int*   __restrict__ nlist,
                    const float* __restrict__ edges,
                    const float* __restrict__ inv_degree,
                    const unsigned short* __restrict__ w2f,
                    float* __restrict__ out)
{
    __shared__ unsigned short tS[TI * LN];            // 32 KiB T (swizzled, R7 layout)
    const int tid    = threadIdx.x;
    const int wv     = __builtin_amdgcn_readfirstlane(tid >> 6);   // wave id 0..7
    const int lane   = tid & 63;
    const int i_base = blockIdx.x * TI;
    char* tB = (char*)tS;
    const unsigned lane4 = (unsigned)lane * 4u;

    // ---------------- stage 1: 2 rows per wave ----------------
    for (int it = 0; it < 2; ++it) {
        const int row = wv * 2 + it;                  // uniform 0..15
        const int i   = i_base + row;
        const int*   nl = nlist + (size_t)i * KNB;
        const float* ep = edges + (size_t)i * (KNB * E);

        float a0[E], a1[E];
        #pragma unroll
        for (int n = 0; n < E; ++n) { a0[n] = 0.f; a1[n] = 0.f; }

        unsigned g[16];
        unsigned vo[8];
        MKVO(0);  ISSUE8(0);                          //  8 in flight (j 0-7)
        MKVO(8);  ISSUE8(8);                          // 16 in flight (j 8-15)
        WAIT8("8", 0);  CONSUME8(0, 0);               // j0-7 landed; 8 flying
        MKVO(16); ISSUE8(0);                          // 16 in flight (j16-23 -> g[0..7])
        WAIT8("8", 8);  CONSUME8(8, 8);               // j8-15 landed; 8 flying
        MKVO(24); ISSUE8(8);                          // 16 in flight (j24-31 -> g[8..15])
        WAIT8("8", 0);  CONSUME8(16, 0);              // j16-23 landed; 8 flying
        WAIT8("0", 8);  CONSUME8(24, 8);              // all done

        // pack 16 bf16 (ln = lane*16 + 0..15 of row), swizzled 16B-slot store (R7)
        uint4 pk0, pk1;
        asm("v_cvt_pk_bf16_f32 %0, %1, %2" : "=v"(pk0.x) : "v"(a0[0]), "v"(a0[1]));
        asm("v_cvt_pk_bf16_f32 %0, %1, %2" : "=v"(pk0.y) : "v"(a0[2]), "v"(a0[3]));
        asm("v_cvt_pk_bf16_f32 %0, %1, %2" : "=v"(pk0.z) : "v"(a0[4]), "v"(a0[5]));
        asm("v_cvt_pk_bf16_f32 %0, %1, %2" : "=v"(pk0.w) : "v"(a0[6]), "v"(a0[7]));
        asm("v_cvt_pk_bf16_f32 %0, %1, %2" : "=v"(pk1.x) : "v"(a1[0]), "v"(a1[1]));
        asm("v_cvt_pk_bf16_f32 %0, %1, %2" : "=v"(pk1.y) : "v"(a1[2]), "v"(a1[3]));
        asm("v_cvt_pk_bf16_f32 %0, %1, %2" : "=v"(pk1.z) : "v"(a1[4]), "v"(a1[5]));
        asm("v_cvt_pk_bf16_f32 %0, %1, %2" : "=v"(pk1.w) : "v"(a1[6]), "v"(a1[7]));
        const int p2 = (lane >> 2) & 1;
        const int s  = (row & 7) << 4;
        const int rb = row * (LN * 2);
        const uint4 first  = p2 ? pk1 : pk0;
        const uint4 second = p2 ? pk0 : pk1;
        *(uint4*)(tB + rb + ((lane * 32 + (p2 << 4))      ^ s)) = first;
        *(uint4*)(tB + rb + ((lane * 32 + 16 - (p2 << 4)) ^ s)) = second;
    }
    __syncthreads();

    // ---------------- stage 2: MFMA, one 16x16 m-tile per wave ----------------
    const int colm = lane & 15;                       // i-row for A, m-col for B/C
    const int kq   = lane >> 4;
    const int mt   = wv;                              // m-tile 0..7

    f32x4 c0 = {0.f, 0.f, 0.f, 0.f};

    const int arow = colm * (LN * 2);
    const int asw  = (colm & 7) << 4;

    #pragma unroll 4
    for (int kb = 0; kb < LN / 32; ++kb) {
        union { short8v v; uint2 u[2]; } af;
        af.u[0] = *(const uint2*)(tB + arow + ((kb * 64      + kq * 8) ^ asw)); // k=kb*32+kq*4+e
        af.u[1] = *(const uint2*)(tB + arow + ((kb * 64 + 32 + kq * 8) ^ asw)); // k=kb*32+16+kq*4+e
        union { short8v v; uint4 u; } b0;
        b0.u = *(const uint4*)(w2f + ((size_t)((kb * 128 + mt * 16 + colm) * 4 + kq)) * 8);
        c0 = __builtin_amdgcn_mfma_f32_16x16x32_bf16(af.v, b0.v, c0, 0, 0, 0);
    }

    // C/D: col = lane&15, row = (lane>>4)*4 + r   [measured m89]
    #pragma unroll
    for (int r = 0; r < 4; ++r) {
        const int ii = kq * 4 + r;
        const int gi = i_base + ii;
        out[(size_t)gi * F + mt * 16 + colm] = inv_degree[gi] * c0[r];
    }
}

// ---------- fallback (round-1 kernel, pure fp32) for tiny ws ----------
__global__ __launch_bounds__(256, 2)
void mp_fused_fallback(const float* __restrict__ nodes, const int* __restrict__ nlist,
                       const float* __restrict__ edges, const float* __restrict__ inv_degree,
                       const float* __restrict__ w, float* __restrict__ out)
{
    __shared__ float tLds[TI * F * E];
    const int tid = threadIdx.x;
    const int i_base = blockIdx.x * TI;
    {
        const int l = tid & (F - 1);
        const int half = __builtin_amdgcn_readfirstlane(tid >> 7);
        for (int g = 0; g < TI / 2; ++g) {
            const int ii = g * 2 + half;
            const int i = i_base + ii;
            float acc[E];
            #pragma unroll
            for (int n = 0; n < E; ++n) acc[n] = 0.f;
            const int* nl = nlist + i * KNB;
            const float* ep = edges + (size_t)i * (KNB * E);
            #pragma unroll 4
            for (int j = 0; j < KNB; ++j) {
                unsigned idx = (unsigned)nl[j];
                if (idx >= (unsigned)NN) idx = 0u;
                const float v = nodes[idx * F + l];
                #pragma unroll
                for (int n = 0; n < E; ++n) acc[n] = __builtin_fmaf(ep[j * E + n], v, acc[n]);
            }
            float4* dst = (float4*)&tLds[ii * (F * E) + l * E];
            dst[0] = make_float4(acc[0], acc[1], acc[2], acc[3]);
            dst[1] = make_float4(acc[4], acc[5], acc[6], acc[7]);
        }
    }
    __syncthreads();
    const int m_lo = tid & 63;
    const int q = __builtin_amdgcn_readfirstlane(tid >> 6);
    float accA[TI], accB[TI];
    #pragma unroll
    for (int ii = 0; ii < TI; ++ii) { accA[ii] = 0.f; accB[ii] = 0.f; }
    for (int lq = 0; lq < F / 4; ++lq) {
        const int l = q * (F / 4) + lq;
        const float4* wp0 = (const float4*)&w[(size_t)l * (F * E) + (size_t)m_lo * E];
        const float4* wp1 = (const float4*)&w[(size_t)l * (F * E) + (size_t)(m_lo + 64) * E];
        const float4 w0a = wp0[0], w0b = wp0[1];
        const float4 w1a = wp1[0], w1b = wp1[1];
        #pragma unroll
        for (int ii = 0; ii < TI; ++ii) {
            const float4* tp = (const float4*)&tLds[ii * (F * E) + l * E];
            const float4 ta = tp[0], tb = tp[1];
            float sA = accA[ii], sB = accB[ii];
            sA = __builtin_fmaf(ta.x, w0a.x, sA); sA = __builtin_fmaf(ta.y, w0a.y, sA);
            sA = __builtin_fmaf(ta.z, w0a.z, sA); sA = __builtin_fmaf(ta.w, w0a.w, sA);
            sA = __builtin_fmaf(tb.x, w0b.x, sA); sA = __builtin_fmaf(tb.y, w0b.y, sA);
            sA = __builtin_fmaf(tb.z, w0b.z, sA); sA = __builtin_fmaf(tb.w, w0b.w, sA);
            sB = __builtin_fmaf(ta.x, w1a.x, sB); sB = __builtin_fmaf(ta.y, w1a.y, sB);
            sB = __builtin_fmaf(ta.z, w1a.z, sB); sB = __builtin_fmaf(ta.w, w1a.w, sB);
            sB = __builtin_fmaf(tb.x, w1b.x, sB); sB = __builtin_fmaf(tb.y, w1b.y, sB);
            sB = __builtin_fmaf(tb.z, w1b.z, sB); sB = __builtin_fmaf(tb.w, w1b.w, sB);
            accA[ii] = sA; accB[ii] = sB;
        }
    }
    __syncthreads();
    float* pLds = tLds;
    #pragma unroll
    for (int ii = 0; ii < TI; ++ii) {
        pLds[q * (TI * F) + ii * F + m_lo] = accA[ii];
        pLds[q * (TI * F) + ii * F + m_lo + 64] = accB[ii];
    }
    __syncthreads();
    #pragma unroll
    for (int r = 0; r < (TI * F) / 256; ++r) {
        const int o = r * 256 + tid;
        const int ii = o >> 7;
        const int m = o & (F - 1);
        const float s = pLds[0 * (TI * F) + ii * F + m] + pLds[1 * (TI * F) + ii * F + m]
                      + pLds[2 * (TI * F) + ii * F + m] + pLds[3 * (TI * F) + ii * F + m];
        const int i = i_base + ii;
        out[(size_t)i * F + m] = inv_degree[i] * s;
    }
}

extern "C" void kernel_launch(void* const* d_in, const int* in_sizes, int n_in,
                              void* d_out, int out_size, void* d_ws, size_t ws_size,
                              hipStream_t stream) {
    const float* nodes      = (const float*)d_in[0];
    const int*   nlist      = (const int*)d_in[1];
    const float* edges      = (const float*)d_in[2];
    const float* inv_degree = (const float*)d_in[3];
    const float* w          = (const float*)d_in[4];
    float* out = (float*)d_out;
    (void)in_sizes; (void)n_in; (void)out_size;

    const size_t need_w2 = (size_t)LN * F * 2;                  // 256 KiB
    const size_t need_nb = (size_t)NN * F * 2;                  // 12.8 MiB

    if (ws_size < need_w2 + need_nb) {
        mp_fused_fallback<<<dim3(NN / TI), dim3(256), 0, stream>>>(
            nodes, nlist, edges, inv_degree, w, out);
        return;
    }
    unsigned short* w2f = (unsigned short*)d_ws;
    unsigned short* nb  = (unsigned short*)((char*)d_ws + need_w2);

    prep_all_kernel<<<dim3(512 + NN * F / 8 / 256), dim3(256), 0, stream>>>(w, w2f, nodes, nb);
    mp_main_kernel<<<dim3(NN / TI), dim3(512), 0, stream>>>(
        nb, nlist, edges, inv_degree, w2f, out);
}